// Round 16
// baseline (671.015 us; speedup 1.0000x reference)
//
#include <hip/hip_runtime.h>

// ---------- helpers ----------
using s16x8 = __attribute__((ext_vector_type(8))) short;
using f32x4 = __attribute__((ext_vector_type(4))) float;

#define MFMA(a, b, c) __builtin_amdgcn_mfma_f32_16x16x32_bf16((a), (b), (c), 0, 0, 0)
#define INVBN 0.9999950000374997f

__device__ __forceinline__ float b2f(unsigned short u) {
    return __uint_as_float(((unsigned int)u) << 16);
}
__device__ __forceinline__ unsigned short f2b(float f) {
    unsigned int x = __float_as_uint(f);
    unsigned int r = x + 0x7FFFu + ((x >> 16) & 1u);
    return (unsigned short)(r >> 16);
}
__device__ __forceinline__ unsigned umin_(unsigned a, unsigned b) { return a < b ? a : b; }
__device__ __forceinline__ unsigned umax_(unsigned a, unsigned b) { return a > b ? a : b; }
#define CE(a, b) { unsigned lo_ = umin_(a, b), hi_ = umax_(a, b); (a) = lo_; (b) = hi_; }

#define BITONIC_RESORT16(v) { \
    _Pragma("unroll") for (int i_ = 0; i_ < 8; i_++) CE(v[i_], v[i_ + 8]) \
    _Pragma("unroll") for (int g_ = 0; g_ < 2; g_++) \
    _Pragma("unroll") for (int i_ = 0; i_ < 4; i_++) CE(v[g_ * 8 + i_], v[g_ * 8 + i_ + 4]) \
    _Pragma("unroll") for (int g_ = 0; g_ < 4; g_++) \
    _Pragma("unroll") for (int i_ = 0; i_ < 2; i_++) CE(v[g_ * 4 + i_], v[g_ * 4 + i_ + 2]) \
    _Pragma("unroll") for (int g_ = 0; g_ < 8; g_++) CE(v[g_ * 2], v[g_ * 2 + 1]) }

// sort8(c8) asc + merge top-16 into v (asc) + resort
#define SORT8_MERGE(c8, v) { \
    CE(c8[0], c8[1]) CE(c8[2], c8[3]) CE(c8[4], c8[5]) CE(c8[6], c8[7]) \
    CE(c8[0], c8[2]) CE(c8[1], c8[3]) CE(c8[4], c8[6]) CE(c8[5], c8[7]) \
    CE(c8[1], c8[2]) CE(c8[5], c8[6]) \
    CE(c8[0], c8[4]) CE(c8[1], c8[5]) CE(c8[2], c8[6]) CE(c8[3], c8[7]) \
    CE(c8[2], c8[4]) CE(c8[3], c8[5]) \
    CE(c8[1], c8[2]) CE(c8[3], c8[4]) CE(c8[5], c8[6]) \
    _Pragma("unroll") for (int i_ = 0; i_ < 8; i_++) v[i_] = umax_(v[i_], c8[7 - i_]); \
    BITONIC_RESORT16(v) }

// cross-lane merge over lanes l^16, l^32 (reversed + max + resort), 2 levels
#define XLANE_MERGE(v) { \
    _Pragma("unroll") for (int lev_ = 0; lev_ < 2; lev_++) { \
        int m_ = lev_ == 0 ? 16 : 32; \
        unsigned o_[16]; \
        _Pragma("unroll") for (int i_ = 0; i_ < 16; i_++) \
            o_[i_] = (unsigned)__shfl_xor((int)v[15 - i_], m_, 64); \
        _Pragma("unroll") for (int i_ = 0; i_ < 16; i_++) v[i_] = umax_(v[i_], o_[i_]); \
        BITONIC_RESORT16(v) } }

// ---------- sparse path (all f32 scalar; tiny) ----------
__global__ __launch_bounds__(256) void k_sparse_u0(const float* sp, const float* dn,
                                                   float* usp0, float* xxsp) {
    int s = blockIdx.x, b = blockIdx.y, c = threadIdx.x;
    float v;
    if (c < 128) {
        v = sp[(b * 128 + c) * 32 + s];
    } else {
        const float* row = dn + ((size_t)((b * 128 + (c - 128)) * 32 + s)) * 128;
        float m = -3.0e38f;
        for (int p = 0; p < 128; p++) m = fmaxf(m, row[p]);
        v = m;
    }
    usp0[(size_t)(b * 32 + s) * 256 + c] = v;
    __shared__ float red[256];
    red[c] = v * v;
    __syncthreads();
    for (int st = 128; st > 0; st >>= 1) {
        if (c < st) red[c] += red[c + st];
        __syncthreads();
    }
    if (c == 0) xxsp[b * 32 + s] = red[0];
}

__global__ __launch_bounds__(64) void k_sparse_knn(const float* usp0, const float* xxsp, int* idxsp) {
    int n = blockIdx.x, b = blockIdx.y, t = threadIdx.x;
    float nd = -3.0e38f;
    if (t < 32) {
        const float* xn = usp0 + (size_t)(b * 32 + n) * 256;
        const float* xj = usp0 + (size_t)(b * 32 + t) * 256;
        float inner = 0.f;
        for (int c = 0; c < 256; c++) inner += xn[c] * xj[c];
        nd = 2.f * inner - xxsp[b * 32 + n] - xxsp[b * 32 + t];
    }
    float best1 = -3.0e38f, best2 = -3.0e38f;
    int i1 = 0, i2 = 0;
    for (int jj = 0; jj < 32; jj++) {
        float vv = __shfl(nd, jj, 64);
        if (vv > best1) { best2 = best1; i2 = i1; best1 = vv; i1 = jj; }
        else if (vv > best2) { best2 = vv; i2 = jj; }
    }
    if (t == 0) {
        idxsp[(b * 32 + n) * 2] = i1;
        idxsp[(b * 32 + n) * 2 + 1] = i2;
    }
}

__global__ __launch_bounds__(256) void k_sparse_edge(const float* usp0, const int* idxsp,
                                                     const float* wsp, const float* bsp,
                                                     const float* gsp, const float* besp,
                                                     float* out) {
    int n = blockIdx.x, b = blockIdx.y, t = threadIdx.x;
    __shared__ float ctr[256], nb0[256], nb1[256];
    int i0 = idxsp[(b * 32 + n) * 2], i1 = idxsp[(b * 32 + n) * 2 + 1];
    ctr[t] = usp0[(size_t)(b * 32 + n) * 256 + t];
    nb0[t] = usp0[(size_t)(b * 32 + i0) * 256 + t];
    nb1[t] = usp0[(size_t)(b * 32 + i1) * 256 + t];
    __syncthreads();
    const float* wrow = wsp + (size_t)t * 512;
    float a0 = 0.f, a1 = 0.f, ac = 0.f;
    for (int c = 0; c < 256; c++) {
        float w1 = wrow[c], w2 = wrow[256 + c];
        float cc = ctr[c];
        a0 += (nb0[c] - cc) * w1;
        a1 += (nb1[c] - cc) * w1;
        ac += cc * w2;
    }
    float g = gsp[t], bb = bsp[t], be = besp[t];
    float h0 = g * INVBN * (a0 + ac + bb) + be;
    float h1 = g * INVBN * (a1 + ac + bb) + be;
    out[((size_t)(b * 256 + t)) * 32 + n] = fmaxf(fmaxf(h0, h1), 0.f);
}

// ---------- dense path ----------
// build + fused row-norm (f64 exact): xx = sum(tile^2) + sum(sp^2) per stroke
__global__ __launch_bounds__(256) void k_build_xdn(const float* sp, const float* dn,
                                                   unsigned short* xdn, float* xdnf,
                                                   float* xx, double* xxd) {
    int bx = blockIdx.x;
    int s = bx >> 2, q = bx & 3;
    int b = blockIdx.y, t = threadIdx.x;
    __shared__ float tile[32 * 131];
    __shared__ double spred[128];
    __shared__ double spsum_sh;
    float spv = 0.f;
    if (t >= 128) spv = sp[(b * 128 + (t - 128)) * 32 + s];
    int pl = t & 31, ch = t >> 5;
#pragma unroll
    for (int it = 0; it < 16; it++) {
        int c = it * 8 + ch;
        tile[pl * 131 + c] = dn[((size_t)((b * 128 + c) * 32 + s)) * 128 + q * 32 + pl];
    }
    if (t >= 128) spred[t - 128] = (double)spv * spv;
    __syncthreads();
    if (t == 0) {
        double ssum = 0.0;
        for (int i = 0; i < 128; i++) ssum += spred[i];
        spsum_sh = ssum;
    }
    for (int pp = 0; pp < 32; pp++) {
        float v = (t < 128) ? tile[pp * 131 + t] : spv;
        size_t row = (size_t)(b * 4096) + s * 128 + q * 32 + pp;
        xdnf[row * 256 + t] = v;
        xdn[row * 256 + t] = f2b(v);
    }
    __syncthreads();
    {
        int pp = t >> 3, seg = t & 7;
        double ps = 0.0;
#pragma unroll
        for (int i = 0; i < 16; i++) {
            float v = tile[pp * 131 + seg * 16 + i];
            ps += (double)v * v;
        }
        ps += __shfl_xor(ps, 1, 64);
        ps += __shfl_xor(ps, 2, 64);
        ps += __shfl_xor(ps, 4, 64);
        if (seg == 0) {
            double tot = ps + spsum_sh;
            size_t row = (size_t)(b * 4096) + s * 128 + q * 32 + pp;
            xx[row] = (float)tot;
            xxd[row] = tot;
        }
    }
}

__global__ __launch_bounds__(256) void k_wcat(const float* wdn, unsigned short* wcat) {
    int j = blockIdx.x, c = threadIdx.x;
    if (j < 256) {
        wcat[j * 256 + c] = f2b(wdn[j * 512 + c]);
    } else {
        int o = j - 256;
        wcat[j * 256 + c] = f2b(wdn[o * 512 + 256 + c] - wdn[o * 512 + c]);
    }
}

// phase-1 kNN: 8 waves, tile-parity groups, 2 ROW-GROUPS per wave (32 rows).
// T14 async-STAGE: next tile preloaded to regs during compute, ds_write at
// top of next iteration -> global latency hidden under MFMA+selection.
__global__ __launch_bounds__(512, 4) void k_dense_knn(const unsigned short* xdn, const float* xx, int* cand) {
    int b = blockIdx.y;
    int rb = blockIdx.x >> 1;
    int h = blockIdx.x & 1;
    int r0 = rb * 128;
    int c0base = h * 2048;
    int t = threadIdx.x;
    int g = t >> 8;          // tile-parity group (waves 0-3 / 4-7)
    int tg = t & 255;        // thread-in-group
    int wr = (t >> 6) & 3;   // row-wave within group
    int l = t & 63;
    __shared__ __align__(16) char smem_raw[2 * 32 * 264 * 2 + 256];   // 34048 B
    unsigned short* acol = (unsigned short*)smem_raw;
    float* xxc = (float*)(smem_raw + 2 * 32 * 264 * 2);
    unsigned* g1k = (unsigned*)smem_raw;   // ALIAS: valid only after post-loop barrier
    size_t bN = (size_t)b * 4096;
    int row0 = wr * 32 + (l & 15);   // relative row of rg0
    int row1 = row0 + 16;            // rg1

    unsigned short* acolg = acol + g * (32 * 264);
    int sr = tg & 31, sseg = tg >> 5;

    // tile-invariant B fragments (my 2 rows) in registers
    s16x8 bfrag0[8], bfrag1[8];
    {
        const s16x8* gb0 = (const s16x8*)(xdn + (bN + r0 + row0) * 256 + (l >> 4) * 8);
        const s16x8* gb1 = (const s16x8*)(xdn + (bN + r0 + row1) * 256 + (l >> 4) * 8);
#pragma unroll
        for (int ks = 0; ks < 8; ks++) { bfrag0[ks] = gb0[ks * 4]; bfrag1[ks] = gb1[ks * 4]; }
    }

    // prologue: preload tile (g) into regs
    s16x8 stg[4];
    float xxstg = 0.f;
    {
        int c0 = c0base + g * 32;
        const s16x8* src = (const s16x8*)(xdn + (bN + c0 + sr) * 256 + sseg * 32);
#pragma unroll
        for (int u = 0; u < 4; u++) stg[u] = src[u];
        if (tg < 32) xxstg = xx[bN + c0 + tg];
    }

    unsigned v16a[16], v16b[16];
#pragma unroll
    for (int i = 0; i < 16; i++) { v16a[i] = 0u; v16b[i] = 0u; }

    for (int ct = 0; ct < 32; ct++) {
        int c0 = c0base + (ct * 2 + g) * 32;
        __syncthreads();   // prev compute done reading acolg
        {
            s16x8* dst = (s16x8*)(acolg + sr * 264 + sseg * 32);
#pragma unroll
            for (int u = 0; u < 4; u++) dst[u] = stg[u];
        }
        if (tg < 32) xxc[g * 32 + tg] = xxstg;
        // issue next tile's global loads now; latency hides under compute
        if (ct < 31) {
            int c0n = c0base + ((ct + 1) * 2 + g) * 32;
            const s16x8* src = (const s16x8*)(xdn + (bN + c0n + sr) * 256 + sseg * 32);
#pragma unroll
            for (int u = 0; u < 4; u++) stg[u] = src[u];
            if (tg < 32) xxstg = xx[bN + c0n + tg];
        }
        __syncthreads();   // staging visible
        f32x4 a00 = {0.f, 0.f, 0.f, 0.f}, a01 = {0.f, 0.f, 0.f, 0.f};
        f32x4 a10 = {0.f, 0.f, 0.f, 0.f}, a11 = {0.f, 0.f, 0.f, 0.f};
        const unsigned short* ap0 = acolg + (l & 15) * 264 + (l >> 4) * 8;
        const unsigned short* ap1 = ap0 + 16 * 264;
#pragma unroll
        for (int ks = 0; ks < 8; ks++) {
            s16x8 ca = *(const s16x8*)(ap0 + ks * 32);
            s16x8 cb = *(const s16x8*)(ap1 + ks * 32);
            a00 = MFMA(ca, bfrag0[ks], a00);
            a01 = MFMA(cb, bfrag0[ks], a01);
            a10 = MFMA(ca, bfrag1[ks], a10);
            a11 = MFMA(cb, bfrag1[ks], a11);
        }
        {
            unsigned c8[8];
#pragma unroll
            for (int j = 0; j < 4; j++) {
                int cl0 = (l >> 4) * 4 + j;
                float d0 = 2.f * a00[j] - xxc[g * 32 + cl0];
                unsigned u0 = __float_as_uint(d0);
                u0 ^= ((unsigned)((int)u0 >> 31)) | 0x80000000u;
                c8[j] = (u0 & 0xFFFFF000u) | (unsigned)(c0 + cl0);
                int cl1 = cl0 + 16;
                float d1 = 2.f * a01[j] - xxc[g * 32 + cl1];
                unsigned u1 = __float_as_uint(d1);
                u1 ^= ((unsigned)((int)u1 >> 31)) | 0x80000000u;
                c8[4 + j] = (u1 & 0xFFFFF000u) | (unsigned)(c0 + cl1);
            }
            SORT8_MERGE(c8, v16a)
        }
        {
            unsigned c8[8];
#pragma unroll
            for (int j = 0; j < 4; j++) {
                int cl0 = (l >> 4) * 4 + j;
                float d0 = 2.f * a10[j] - xxc[g * 32 + cl0];
                unsigned u0 = __float_as_uint(d0);
                u0 ^= ((unsigned)((int)u0 >> 31)) | 0x80000000u;
                c8[j] = (u0 & 0xFFFFF000u) | (unsigned)(c0 + cl0);
                int cl1 = cl0 + 16;
                float d1 = 2.f * a11[j] - xxc[g * 32 + cl1];
                unsigned u1 = __float_as_uint(d1);
                u1 ^= ((unsigned)((int)u1 >> 31)) | 0x80000000u;
                c8[4 + j] = (u1 & 0xFFFFF000u) | (unsigned)(c0 + cl1);
            }
            SORT8_MERGE(c8, v16b)
        }
    }

    XLANE_MERGE(v16a)
    XLANE_MERGE(v16b)

    // fence: all waves done with acol before g1k (aliased) is written
    __syncthreads();
    if (g == 1 && (l >> 4) == 0) {
#pragma unroll
        for (int i = 0; i < 16; i++) {
            g1k[row0 * 16 + i] = v16a[i];
            g1k[row1 * 16 + i] = v16b[i];
        }
    }
    __syncthreads();
    if (g == 0 && (l >> 4) == 0) {
        {
            unsigned o[16];
#pragma unroll
            for (int i = 0; i < 16; i++) o[i] = g1k[row0 * 16 + 15 - i];
#pragma unroll
            for (int i = 0; i < 16; i++) v16a[i] = umax_(v16a[i], o[i]);
            BITONIC_RESORT16(v16a)
            int* dst = cand + (bN + r0 + row0) * 32 + h * 16;
#pragma unroll
            for (int i = 0; i < 16; i++) dst[i] = (int)(v16a[i] & 0xFFFu);
        }
        {
            unsigned o[16];
#pragma unroll
            for (int i = 0; i < 16; i++) o[i] = g1k[row1 * 16 + 15 - i];
#pragma unroll
            for (int i = 0; i < 16; i++) v16b[i] = umax_(v16b[i], o[i]);
            BITONIC_RESORT16(v16b)
            int* dst = cand + (bN + r0 + row1) * 32 + h * 16;
#pragma unroll
            for (int i = 0; i < 16; i++) dst[i] = (int)(v16b[i] & 0xFFFu);
        }
    }
}

// phase-2: exact f64 re-rank of 32 candidates -> top-10 indices.
// Coalesced gather (4 lanes/candidate) + XCD-affinity swizzle (b = flat & 7).
__global__ __launch_bounds__(256) void k_rerank(const float* xdnf, const double* xxd,
                                                const int* cand, int* idxdn) {
    int flat = blockIdx.x;
    int b = flat & 7;
    int n0 = (flat >> 3) * 8;
    int t = threadIdx.x;
    int r = t >> 5;          // row 0..7
    int qg = (t >> 2) & 7;   // candidate-in-pass 0..7
    int chunk = t & 3;       // 16B chunk within a 64B line
    __shared__ float xa[8][260];
    __shared__ double dred[8][32];
    __shared__ double xxdn[8];
    __shared__ int cidx[8][32];
    size_t bN = (size_t)b * 4096;
    {
        int rr = t >> 5, qq = t & 31;
        const float* src = xdnf + (bN + n0 + rr) * 256 + qq * 8;
        *(f32x4*)&xa[rr][qq * 8] = *(const f32x4*)src;
        *(f32x4*)&xa[rr][qq * 8 + 4] = *(const f32x4*)(src + 4);
        if (t < 8) xxdn[t] = xxd[bN + n0 + t];
        cidx[rr][qq] = cand[(bN + n0 + rr) * 32 + qq];
    }
    __syncthreads();
#pragma unroll
    for (int p = 0; p < 4; p++) {
        int q = p * 8 + qg;
        int j = cidx[r][q];
        const float* xb = xdnf + (bN + j) * 256 + chunk * 4;
        const float* xav = &xa[r][chunk * 4];
        double ac0 = 0.0, ac1 = 0.0, ac2 = 0.0, ac3 = 0.0;
#pragma unroll 8
        for (int c4 = 0; c4 < 16; c4++) {
            f32x4 a = *(const f32x4*)(xav + c4 * 16);
            f32x4 bb = *(const f32x4*)(xb + c4 * 16);
            ac0 += (double)a[0] * bb[0];
            ac1 += (double)a[1] * bb[1];
            ac2 += (double)a[2] * bb[2];
            ac3 += (double)a[3] * bb[3];
        }
        double acc = (ac0 + ac1) + (ac2 + ac3);
        acc += __shfl_xor(acc, 1, 64);
        acc += __shfl_xor(acc, 2, 64);
        if (chunk == 0)
            dred[r][q] = 2.0 * acc - xxdn[r] - xxd[bN + j];
    }
    __syncthreads();
    if (t < 8) {
        int used = 0;
        int* dst = idxdn + (bN + n0 + t) * 10;
        for (int rank = 0; rank < 10; rank++) {
            double best = -1.0e300;
            int bi = 0;
#pragma unroll
            for (int i = 0; i < 32; i++) {
                bool ok = !((used >> i) & 1) && dred[t][i] > best;
                if (ok) { best = dred[t][i]; bi = i; }
            }
            used |= (1 << bi);
            dst[rank] = cidx[t][bi];
        }
    }
}

// C_pq[b][n][j] bf16, j<256: P = X.W1^T, j>=256: Q = X.dW^T
// 2 j-tiles per block, arow staged once
__global__ __launch_bounds__(256) void k_pq_gemm(const unsigned short* xdn, const unsigned short* wcat,
                                                 unsigned short* cpq) {
    int j0 = blockIdx.x * 64;
    int n0 = blockIdx.y * 64;
    int b = blockIdx.z;
    int t = threadIdx.x, w = t >> 6, l = t & 63;
    __shared__ __align__(16) unsigned short arow[64 * 264];
    __shared__ __align__(16) unsigned short brow[32 * 264];
    __shared__ float outb[64 * 34];
    {
        int r = t >> 2, seg = t & 3;
        const unsigned short* src = xdn + ((size_t)b * 4096 + n0 + r) * 256 + seg * 64;
        unsigned short* dst = arow + r * 264 + seg * 64;
#pragma unroll
        for (int u = 0; u < 8; u++) *(s16x8*)(dst + 8 * u) = *(const s16x8*)(src + 8 * u);
    }
    {
        int r = t >> 3, seg = t & 7;
        const unsigned short* src = wcat + (size_t)(j0 + r) * 256 + seg * 32;
        unsigned short* dst = brow + r * 264 + seg * 32;
#pragma unroll
        for (int u = 0; u < 4; u++) *(s16x8*)(dst + 8 * u) = *(const s16x8*)(src + 8 * u);
    }
    __syncthreads();
    const unsigned short* ap = arow + (w * 16 + (l & 15)) * 264 + (l >> 4) * 8;
    const unsigned short* bp0 = brow + (l & 15) * 264 + (l >> 4) * 8;
    const unsigned short* bp1 = brow + (16 + (l & 15)) * 264 + (l >> 4) * 8;
#pragma unroll
    for (int jt = 0; jt < 2; jt++) {
        f32x4 acc0 = {0.f, 0.f, 0.f, 0.f}, acc1 = {0.f, 0.f, 0.f, 0.f};
#pragma unroll
        for (int ks = 0; ks < 8; ks++) {
            s16x8 af = *(const s16x8*)(ap + ks * 32);
            acc0 = MFMA(af, *(const s16x8*)(bp0 + ks * 32), acc0);
            acc1 = MFMA(af, *(const s16x8*)(bp1 + ks * 32), acc1);
        }
        __syncthreads();
        if (jt == 0) {
            int r = t >> 3, seg = t & 7;
            const unsigned short* src = wcat + (size_t)(j0 + 32 + r) * 256 + seg * 32;
            unsigned short* dst = brow + r * 264 + seg * 32;
#pragma unroll
            for (int u = 0; u < 4; u++) *(s16x8*)(dst + 8 * u) = *(const s16x8*)(src + 8 * u);
        }
#pragma unroll
        for (int j = 0; j < 4; j++) {
            int row = w * 16 + (l >> 4) * 4 + j;
            outb[row * 34 + (l & 15)] = acc0[j];
            outb[row * 34 + 16 + (l & 15)] = acc1[j];
        }
        __syncthreads();
#pragma unroll
        for (int it = 0; it < 8; it++) {
            int r = it * 8 + (t >> 5);
            int c = t & 31;
            cpq[((size_t)b * 4096 + n0 + r) * 512 + j0 + jt * 32 + c] = f2b(outb[r * 34 + c]);
        }
    }
}

// XCD-affinity swizzle: b = flat & 7; pad rows fused (p==0 / p==127)
__global__ __launch_bounds__(256) void k_combine(const unsigned short* cpq, const int* idxdn,
                                                 const float* bdn, const float* gdn,
                                                 const float* bedn, unsigned short* upad) {
    int flat = blockIdx.x;
    int b = flat & 7;
    int n = flat >> 3;
    int s = n >> 7, p = n & 127;
    int t = threadIdx.x;
    const int* ix = idxdn + ((size_t)b * 4096 + n) * 10;
    float qv = b2f(cpq[((size_t)b * 4096 + n) * 512 + 256 + t]);
    float g = gdn[t], bb = bdn[t], be = bedn[t];
    float a = g * INVBN;
    float d = a * (qv + bb) + be;
    float m = -3.0e38f;
#pragma unroll
    for (int kk = 0; kk < 10; kk++) {
        int j = ix[kk];
        float pv = b2f(cpq[((size_t)b * 4096 + j) * 512 + t]);
        m = fmaxf(m, a * pv + d);
    }
    size_t sb = ((size_t)(b * 32 + s)) * 130;
    upad[(sb + 1 + p) * 256 + t] = f2b(fmaxf(m, 0.f));
    if (p == 0) upad[sb * 256 + t] = 0;
    if (p == 127) upad[(sb + 129) * 256 + t] = 0;
}

__global__ void k_wconv_r(const float* wcv, unsigned short* wr) {
    int o = blockIdx.x, c = threadIdx.x;
#pragma unroll
    for (int i = 0; i < 3; i++) wr[o * 768 + i * 256 + c] = f2b(wcv[o * 768 + c * 3 + i]);
}

__global__ __launch_bounds__(256) void k_conv(const unsigned short* upad, const unsigned short* wr,
                                              const float* bcv, const float* gc,
                                              const float* bec, float* out) {
    int j0 = blockIdx.x * 64;
    int mb = blockIdx.y;
    int b = mb >> 5, s = mb & 31;
    int t = threadIdx.x, w = t >> 6, l = t & 63;
    __shared__ __align__(16) unsigned short at[64 * 72];
    __shared__ __align__(16) unsigned short bt[64 * 72];
    __shared__ float outb[64 * 66];
    f32x4 acc[4];
#pragma unroll
    for (int i = 0; i < 4; i++) acc[i] = (f32x4){0.f, 0.f, 0.f, 0.f};
    const size_t abase = ((size_t)(b * 32 + s)) * 130 * 256;
    for (int kc = 0; kc < 12; kc++) {
        __syncthreads();
        {
            int r = t >> 2, seg = t & 3;
            const unsigned short* src = upad + abase + (size_t)(2 * r) * 256 + kc * 64 + seg * 16;
            unsigned short* dst = at + r * 72 + seg * 16;
            *(s16x8*)dst = *(const s16x8*)src;
            *(s16x8*)(dst + 8) = *(const s16x8*)(src + 8);
            const unsigned short* src2 = wr + (size_t)(j0 + r) * 768 + kc * 64 + seg * 16;
            unsigned short* dst2 = bt + r * 72 + seg * 16;
            *(s16x8*)dst2 = *(const s16x8*)src2;
            *(s16x8*)(dst2 + 8) = *(const s16x8*)(src2 + 8);
        }
        __syncthreads();
#pragma unroll
        for (int ks = 0; ks < 2; ks++) {
            s16x8 af = *(const s16x8*)(at + (w * 16 + (l & 15)) * 72 + ks * 32 + (l >> 4) * 8);
#pragma unroll
            for (int cs = 0; cs < 4; cs++) {
                s16x8 bf = *(const s16x8*)(bt + (cs * 16 + (l & 15)) * 72 + ks * 32 + (l >> 4) * 8);
                acc[cs] = MFMA(af, bf, acc[cs]);
            }
        }
    }
    __syncthreads();
#pragma unroll
    for (int cs = 0; cs < 4; cs++)
#pragma unroll
        for (int j = 0; j < 4; j++)
            outb[(w * 16 + (l >> 4) * 4 + j) * 66 + cs * 16 + (l & 15)] = acc[cs][j];
    __syncthreads();
#pragma unroll
    for (int it = 0; it < 16; it++) {
        int oo = it * 4 + (t >> 6);
        int q = t & 63;
        int o = j0 + oo;
        float v = outb[q * 66 + oo];
        float y = fmaxf(gc[o] * INVBN * (v + bcv[o]) + bec[o], 0.f);
        out[65536 + (((size_t)(b * 256 + o)) * 32 + s) * 64 + q] = y;
    }
}

extern "C" void kernel_launch(void* const* d_in, const int* in_sizes, int n_in,
                              void* d_out, int out_size, void* d_ws, size_t ws_size,
                              hipStream_t stream) {
    const float* sp = (const float*)d_in[0];
    const float* dn = (const float*)d_in[1];
    const float* Wsp = (const float*)d_in[2];
    const float* bsp = (const float*)d_in[3];
    const float* gsp = (const float*)d_in[4];
    const float* besp = (const float*)d_in[5];
    const float* Wdn = (const float*)d_in[6];
    const float* bdn = (const float*)d_in[7];
    const float* gdn = (const float*)d_in[8];
    const float* bedn = (const float*)d_in[9];
    const float* Wcv = (const float*)d_in[10];
    const float* bcv = (const float*)d_in[11];
    const float* gc = (const float*)d_in[12];
    const float* bec = (const float*)d_in[13];
    float* out = (float*)d_out;
    char* ws = (char*)d_ws;

    size_t o_xdn = 0;                          // 16,777,216  (bf16 X)
    size_t o_xdnf = o_xdn + 16777216;          // 33,554,432  (f32 X)
    size_t o_cpq = o_xdnf + 33554432;          // 33,554,432  (bf16 P|Q)
    size_t o_upad = o_cpq + 33554432;          // 17,039,360
    size_t o_wcat = o_upad + 17039360;         // 262,144
    size_t o_wr = o_wcat + 262144;             // 393,216
    size_t o_xx = o_wr + 393216;               // 131,072  (f32)
    size_t o_xxd = o_xx + 131072;              // 262,144  (f64)
    size_t o_cand = o_xxd + 262144;            // 4,194,304 (32 cands)
    size_t o_idx = o_cand + 4194304;           // 1,310,720 (top-10)
    size_t o_usp0 = o_idx + 1310720;           // 262,144
    size_t o_xxsp = o_usp0 + 262144;           // 1,024
    size_t o_idxsp = o_xxsp + 1024;            // 2,048

    unsigned short* xdn = (unsigned short*)(ws + o_xdn);
    float* xdnf = (float*)(ws + o_xdnf);
    unsigned short* cpq = (unsigned short*)(ws + o_cpq);
    unsigned short* upad = (unsigned short*)(ws + o_upad);
    unsigned short* wcat = (unsigned short*)(ws + o_wcat);
    unsigned short* wr = (unsigned short*)(ws + o_wr);
    float* xx = (float*)(ws + o_xx);
    double* xxd = (double*)(ws + o_xxd);
    int* cand = (int*)(ws + o_cand);
    int* idxdn = (int*)(ws + o_idx);
    float* usp0 = (float*)(ws + o_usp0);
    float* xxsp = (float*)(ws + o_xxsp);
    int* idxsp = (int*)(ws + o_idxsp);

    // sparse path
    k_sparse_u0<<<dim3(32, 8), 256, 0, stream>>>(sp, dn, usp0, xxsp);
    k_sparse_knn<<<dim3(32, 8), 64, 0, stream>>>(usp0, xxsp, idxsp);
    k_sparse_edge<<<dim3(32, 8), 256, 0, stream>>>(usp0, idxsp, Wsp, bsp, gsp, besp, out);

    // dense path
    k_build_xdn<<<dim3(128, 8), 256, 0, stream>>>(sp, dn, xdn, xdnf, xx, xxd);
    k_wcat<<<dim3(512), 256, 0, stream>>>(Wdn, wcat);
    k_dense_knn<<<dim3(64, 8), 512, 0, stream>>>(xdn, xx, cand);
    k_rerank<<<dim3(4096), 256, 0, stream>>>(xdnf, xxd, cand, idxdn);
    k_pq_gemm<<<dim3(8, 64, 8), 256, 0, stream>>>(xdn, wcat, cpq);
    k_combine<<<dim3(32768), 256, 0, stream>>>(cpq, idxdn, bdn, gdn, bedn, upad);

    // downsample conv
    k_wconv_r<<<dim3(256), 256, 0, stream>>>(Wcv, wr);
    k_conv<<<dim3(4, 256), 256, 0, stream>>>(upad, wr, bcv, gc, bec, out);
}

// Round 17
// 370.113 us; speedup vs baseline: 1.8130x; 1.8130x over previous
//
#include <hip/hip_runtime.h>

// ---------- helpers ----------
using s16x8 = __attribute__((ext_vector_type(8))) short;
using f32x4 = __attribute__((ext_vector_type(4))) float;

#define MFMA(a, b, c) __builtin_amdgcn_mfma_f32_16x16x32_bf16((a), (b), (c), 0, 0, 0)
#define INVBN 0.9999950000374997f

__device__ __forceinline__ float b2f(unsigned short u) {
    return __uint_as_float(((unsigned int)u) << 16);
}
__device__ __forceinline__ unsigned short f2b(float f) {
    unsigned int x = __float_as_uint(f);
    unsigned int r = x + 0x7FFFu + ((x >> 16) & 1u);
    return (unsigned short)(r >> 16);
}
__device__ __forceinline__ unsigned umin_(unsigned a, unsigned b) { return a < b ? a : b; }
__device__ __forceinline__ unsigned umax_(unsigned a, unsigned b) { return a > b ? a : b; }
#define CE(a, b) { unsigned lo_ = umin_(a, b), hi_ = umax_(a, b); (a) = lo_; (b) = hi_; }

#define BITONIC_RESORT16(v) { \
    _Pragma("unroll") for (int i_ = 0; i_ < 8; i_++) CE(v[i_], v[i_ + 8]) \
    _Pragma("unroll") for (int g_ = 0; g_ < 2; g_++) \
    _Pragma("unroll") for (int i_ = 0; i_ < 4; i_++) CE(v[g_ * 8 + i_], v[g_ * 8 + i_ + 4]) \
    _Pragma("unroll") for (int g_ = 0; g_ < 4; g_++) \
    _Pragma("unroll") for (int i_ = 0; i_ < 2; i_++) CE(v[g_ * 4 + i_], v[g_ * 4 + i_ + 2]) \
    _Pragma("unroll") for (int g_ = 0; g_ < 8; g_++) CE(v[g_ * 2], v[g_ * 2 + 1]) }

// sort8(c8) asc + merge top-16 into v (asc) + resort
#define SORT8_MERGE(c8, v) { \
    CE(c8[0], c8[1]) CE(c8[2], c8[3]) CE(c8[4], c8[5]) CE(c8[6], c8[7]) \
    CE(c8[0], c8[2]) CE(c8[1], c8[3]) CE(c8[4], c8[6]) CE(c8[5], c8[7]) \
    CE(c8[1], c8[2]) CE(c8[5], c8[6]) \
    CE(c8[0], c8[4]) CE(c8[1], c8[5]) CE(c8[2], c8[6]) CE(c8[3], c8[7]) \
    CE(c8[2], c8[4]) CE(c8[3], c8[5]) \
    CE(c8[1], c8[2]) CE(c8[3], c8[4]) CE(c8[5], c8[6]) \
    _Pragma("unroll") for (int i_ = 0; i_ < 8; i_++) v[i_] = umax_(v[i_], c8[7 - i_]); \
    BITONIC_RESORT16(v) }

// cross-lane merge over lanes l^16, l^32 (reversed + max + resort), 2 levels
#define XLANE_MERGE(v) { \
    _Pragma("unroll") for (int lev_ = 0; lev_ < 2; lev_++) { \
        int m_ = lev_ == 0 ? 16 : 32; \
        unsigned o_[16]; \
        _Pragma("unroll") for (int i_ = 0; i_ < 16; i_++) \
            o_[i_] = (unsigned)__shfl_xor((int)v[15 - i_], m_, 64); \
        _Pragma("unroll") for (int i_ = 0; i_ < 16; i_++) v[i_] = umax_(v[i_], o_[i_]); \
        BITONIC_RESORT16(v) } }

// ---------- sparse path (all f32 scalar; tiny) ----------
__global__ __launch_bounds__(256) void k_sparse_u0(const float* sp, const float* dn,
                                                   float* usp0, float* xxsp) {
    int s = blockIdx.x, b = blockIdx.y, c = threadIdx.x;
    float v;
    if (c < 128) {
        v = sp[(b * 128 + c) * 32 + s];
    } else {
        const float* row = dn + ((size_t)((b * 128 + (c - 128)) * 32 + s)) * 128;
        float m = -3.0e38f;
        for (int p = 0; p < 128; p++) m = fmaxf(m, row[p]);
        v = m;
    }
    usp0[(size_t)(b * 32 + s) * 256 + c] = v;
    __shared__ float red[256];
    red[c] = v * v;
    __syncthreads();
    for (int st = 128; st > 0; st >>= 1) {
        if (c < st) red[c] += red[c + st];
        __syncthreads();
    }
    if (c == 0) xxsp[b * 32 + s] = red[0];
}

__global__ __launch_bounds__(64) void k_sparse_knn(const float* usp0, const float* xxsp, int* idxsp) {
    int n = blockIdx.x, b = blockIdx.y, t = threadIdx.x;
    float nd = -3.0e38f;
    if (t < 32) {
        const float* xn = usp0 + (size_t)(b * 32 + n) * 256;
        const float* xj = usp0 + (size_t)(b * 32 + t) * 256;
        float inner = 0.f;
        for (int c = 0; c < 256; c++) inner += xn[c] * xj[c];
        nd = 2.f * inner - xxsp[b * 32 + n] - xxsp[b * 32 + t];
    }
    float best1 = -3.0e38f, best2 = -3.0e38f;
    int i1 = 0, i2 = 0;
    for (int jj = 0; jj < 32; jj++) {
        float vv = __shfl(nd, jj, 64);
        if (vv > best1) { best2 = best1; i2 = i1; best1 = vv; i1 = jj; }
        else if (vv > best2) { best2 = vv; i2 = jj; }
    }
    if (t == 0) {
        idxsp[(b * 32 + n) * 2] = i1;
        idxsp[(b * 32 + n) * 2 + 1] = i2;
    }
}

__global__ __launch_bounds__(256) void k_sparse_edge(const float* usp0, const int* idxsp,
                                                     const float* wsp, const float* bsp,
                                                     const float* gsp, const float* besp,
                                                     float* out) {
    int n = blockIdx.x, b = blockIdx.y, t = threadIdx.x;
    __shared__ float ctr[256], nb0[256], nb1[256];
    int i0 = idxsp[(b * 32 + n) * 2], i1 = idxsp[(b * 32 + n) * 2 + 1];
    ctr[t] = usp0[(size_t)(b * 32 + n) * 256 + t];
    nb0[t] = usp0[(size_t)(b * 32 + i0) * 256 + t];
    nb1[t] = usp0[(size_t)(b * 32 + i1) * 256 + t];
    __syncthreads();
    const float* wrow = wsp + (size_t)t * 512;
    float a0 = 0.f, a1 = 0.f, ac = 0.f;
    for (int c = 0; c < 256; c++) {
        float w1 = wrow[c], w2 = wrow[256 + c];
        float cc = ctr[c];
        a0 += (nb0[c] - cc) * w1;
        a1 += (nb1[c] - cc) * w1;
        ac += cc * w2;
    }
    float g = gsp[t], bb = bsp[t], be = besp[t];
    float h0 = g * INVBN * (a0 + ac + bb) + be;
    float h1 = g * INVBN * (a1 + ac + bb) + be;
    out[((size_t)(b * 256 + t)) * 32 + n] = fmaxf(fmaxf(h0, h1), 0.f);
}

// ---------- dense path ----------
// build + fused row-norm (f64 exact): xx = sum(tile^2) + sum(sp^2) per stroke
__global__ __launch_bounds__(256) void k_build_xdn(const float* sp, const float* dn,
                                                   unsigned short* xdn, float* xdnf,
                                                   float* xx, double* xxd) {
    int bx = blockIdx.x;
    int s = bx >> 2, q = bx & 3;
    int b = blockIdx.y, t = threadIdx.x;
    __shared__ float tile[32 * 131];
    __shared__ double spred[128];
    __shared__ double spsum_sh;
    float spv = 0.f;
    if (t >= 128) spv = sp[(b * 128 + (t - 128)) * 32 + s];
    int pl = t & 31, ch = t >> 5;
#pragma unroll
    for (int it = 0; it < 16; it++) {
        int c = it * 8 + ch;
        tile[pl * 131 + c] = dn[((size_t)((b * 128 + c) * 32 + s)) * 128 + q * 32 + pl];
    }
    if (t >= 128) spred[t - 128] = (double)spv * spv;
    __syncthreads();
    if (t == 0) {
        double ssum = 0.0;
        for (int i = 0; i < 128; i++) ssum += spred[i];
        spsum_sh = ssum;
    }
    for (int pp = 0; pp < 32; pp++) {
        float v = (t < 128) ? tile[pp * 131 + t] : spv;
        size_t row = (size_t)(b * 4096) + s * 128 + q * 32 + pp;
        xdnf[row * 256 + t] = v;
        xdn[row * 256 + t] = f2b(v);
    }
    __syncthreads();
    {
        int pp = t >> 3, seg = t & 7;
        double ps = 0.0;
#pragma unroll
        for (int i = 0; i < 16; i++) {
            float v = tile[pp * 131 + seg * 16 + i];
            ps += (double)v * v;
        }
        ps += __shfl_xor(ps, 1, 64);
        ps += __shfl_xor(ps, 2, 64);
        ps += __shfl_xor(ps, 4, 64);
        if (seg == 0) {
            double tot = ps + spsum_sh;
            size_t row = (size_t)(b * 4096) + s * 128 + q * 32 + pp;
            xx[row] = (float)tot;
            xxd[row] = tot;
        }
    }
}

__global__ __launch_bounds__(256) void k_wcat(const float* wdn, unsigned short* wcat) {
    int j = blockIdx.x, c = threadIdx.x;
    if (j < 256) {
        wcat[j * 256 + c] = f2b(wdn[j * 512 + c]);
    } else {
        int o = j - 256;
        wcat[j * 256 + c] = f2b(wdn[o * 512 + 256 + c] - wdn[o * 512 + c]);
    }
}

// phase-1 kNN: 8 waves, tile-parity groups, 2 ROW-GROUPS per wave (32 rows).
// R15 form (proven 158us): direct global->LDS staging, 34KB LDS alias.
// R16's reg-prefetch spilled to scratch (WRITE 364MB) -> REVERTED.
__global__ __launch_bounds__(512, 4) void k_dense_knn(const unsigned short* xdn, const float* xx, int* cand) {
    int b = blockIdx.y;
    int rb = blockIdx.x >> 1;
    int h = blockIdx.x & 1;
    int r0 = rb * 128;
    int c0base = h * 2048;
    int t = threadIdx.x;
    int g = t >> 8;          // tile-parity group (waves 0-3 / 4-7)
    int tg = t & 255;        // thread-in-group
    int wr = (t >> 6) & 3;   // row-wave within group
    int l = t & 63;
    __shared__ __align__(16) char smem_raw[2 * 32 * 264 * 2 + 256];   // 34048 B
    unsigned short* acol = (unsigned short*)smem_raw;
    float* xxc = (float*)(smem_raw + 2 * 32 * 264 * 2);
    unsigned* g1k = (unsigned*)smem_raw;   // ALIAS: valid only after post-loop barrier
    size_t bN = (size_t)b * 4096;
    int row0 = wr * 32 + (l & 15);   // relative row of rg0
    int row1 = row0 + 16;            // rg1

    unsigned short* acolg = acol + g * (32 * 264);

    // tile-invariant B fragments (my 2 rows) in registers
    s16x8 bfrag0[8], bfrag1[8];
    {
        const s16x8* gb0 = (const s16x8*)(xdn + (bN + r0 + row0) * 256 + (l >> 4) * 8);
        const s16x8* gb1 = (const s16x8*)(xdn + (bN + r0 + row1) * 256 + (l >> 4) * 8);
#pragma unroll
        for (int ks = 0; ks < 8; ks++) { bfrag0[ks] = gb0[ks * 4]; bfrag1[ks] = gb1[ks * 4]; }
    }

    unsigned v16a[16], v16b[16];
#pragma unroll
    for (int i = 0; i < 16; i++) { v16a[i] = 0u; v16b[i] = 0u; }

    for (int ct = 0; ct < 32; ct++) {
        int c0 = c0base + (ct * 2 + g) * 32;
        __syncthreads();
        {
            int r = tg & 31, seg = tg >> 5;
            const s16x8* src = (const s16x8*)(xdn + (bN + c0 + r) * 256 + seg * 32);
            s16x8* dst = (s16x8*)(acolg + r * 264 + seg * 32);
#pragma unroll
            for (int u = 0; u < 4; u++) dst[u] = src[u];
        }
        if (tg < 32) xxc[g * 32 + tg] = xx[bN + c0 + tg];
        __syncthreads();
        f32x4 a00 = {0.f, 0.f, 0.f, 0.f}, a01 = {0.f, 0.f, 0.f, 0.f};
        f32x4 a10 = {0.f, 0.f, 0.f, 0.f}, a11 = {0.f, 0.f, 0.f, 0.f};
        const unsigned short* ap0 = acolg + (l & 15) * 264 + (l >> 4) * 8;
        const unsigned short* ap1 = ap0 + 16 * 264;
#pragma unroll
        for (int ks = 0; ks < 8; ks++) {
            s16x8 ca = *(const s16x8*)(ap0 + ks * 32);
            s16x8 cb = *(const s16x8*)(ap1 + ks * 32);
            a00 = MFMA(ca, bfrag0[ks], a00);
            a01 = MFMA(cb, bfrag0[ks], a01);
            a10 = MFMA(ca, bfrag1[ks], a10);
            a11 = MFMA(cb, bfrag1[ks], a11);
        }
        {
            unsigned c8[8];
#pragma unroll
            for (int j = 0; j < 4; j++) {
                int cl0 = (l >> 4) * 4 + j;
                float d0 = 2.f * a00[j] - xxc[g * 32 + cl0];
                unsigned u0 = __float_as_uint(d0);
                u0 ^= ((unsigned)((int)u0 >> 31)) | 0x80000000u;
                c8[j] = (u0 & 0xFFFFF000u) | (unsigned)(c0 + cl0);
                int cl1 = cl0 + 16;
                float d1 = 2.f * a01[j] - xxc[g * 32 + cl1];
                unsigned u1 = __float_as_uint(d1);
                u1 ^= ((unsigned)((int)u1 >> 31)) | 0x80000000u;
                c8[4 + j] = (u1 & 0xFFFFF000u) | (unsigned)(c0 + cl1);
            }
            SORT8_MERGE(c8, v16a)
        }
        {
            unsigned c8[8];
#pragma unroll
            for (int j = 0; j < 4; j++) {
                int cl0 = (l >> 4) * 4 + j;
                float d0 = 2.f * a10[j] - xxc[g * 32 + cl0];
                unsigned u0 = __float_as_uint(d0);
                u0 ^= ((unsigned)((int)u0 >> 31)) | 0x80000000u;
                c8[j] = (u0 & 0xFFFFF000u) | (unsigned)(c0 + cl0);
                int cl1 = cl0 + 16;
                float d1 = 2.f * a11[j] - xxc[g * 32 + cl1];
                unsigned u1 = __float_as_uint(d1);
                u1 ^= ((unsigned)((int)u1 >> 31)) | 0x80000000u;
                c8[4 + j] = (u1 & 0xFFFFF000u) | (unsigned)(c0 + cl1);
            }
            SORT8_MERGE(c8, v16b)
        }
    }

    XLANE_MERGE(v16a)
    XLANE_MERGE(v16b)

    // fence: all waves done with acol before g1k (aliased) is written
    __syncthreads();
    if (g == 1 && (l >> 4) == 0) {
#pragma unroll
        for (int i = 0; i < 16; i++) {
            g1k[row0 * 16 + i] = v16a[i];
            g1k[row1 * 16 + i] = v16b[i];
        }
    }
    __syncthreads();
    if (g == 0 && (l >> 4) == 0) {
        {
            unsigned o[16];
#pragma unroll
            for (int i = 0; i < 16; i++) o[i] = g1k[row0 * 16 + 15 - i];
#pragma unroll
            for (int i = 0; i < 16; i++) v16a[i] = umax_(v16a[i], o[i]);
            BITONIC_RESORT16(v16a)
            int* dst = cand + (bN + r0 + row0) * 32 + h * 16;
#pragma unroll
            for (int i = 0; i < 16; i++) dst[i] = (int)(v16a[i] & 0xFFFu);
        }
        {
            unsigned o[16];
#pragma unroll
            for (int i = 0; i < 16; i++) o[i] = g1k[row1 * 16 + 15 - i];
#pragma unroll
            for (int i = 0; i < 16; i++) v16b[i] = umax_(v16b[i], o[i]);
            BITONIC_RESORT16(v16b)
            int* dst = cand + (bN + r0 + row1) * 32 + h * 16;
#pragma unroll
            for (int i = 0; i < 16; i++) dst[i] = (int)(v16b[i] & 0xFFFu);
        }
    }
}

// phase-2: exact f64 re-rank of 32 candidates -> top-10 indices.
// Coalesced gather (4 lanes/candidate) + XCD-affinity swizzle (b = flat & 7).
__global__ __launch_bounds__(256) void k_rerank(const float* xdnf, const double* xxd,
                                                const int* cand, int* idxdn) {
    int flat = blockIdx.x;
    int b = flat & 7;
    int n0 = (flat >> 3) * 8;
    int t = threadIdx.x;
    int r = t >> 5;          // row 0..7
    int qg = (t >> 2) & 7;   // candidate-in-pass 0..7
    int chunk = t & 3;       // 16B chunk within a 64B line
    __shared__ float xa[8][260];
    __shared__ double dred[8][32];
    __shared__ double xxdn[8];
    __shared__ int cidx[8][32];
    size_t bN = (size_t)b * 4096;
    {
        int rr = t >> 5, qq = t & 31;
        const float* src = xdnf + (bN + n0 + rr) * 256 + qq * 8;
        *(f32x4*)&xa[rr][qq * 8] = *(const f32x4*)src;
        *(f32x4*)&xa[rr][qq * 8 + 4] = *(const f32x4*)(src + 4);
        if (t < 8) xxdn[t] = xxd[bN + n0 + t];
        cidx[rr][qq] = cand[(bN + n0 + rr) * 32 + qq];
    }
    __syncthreads();
#pragma unroll
    for (int p = 0; p < 4; p++) {
        int q = p * 8 + qg;
        int j = cidx[r][q];
        const float* xb = xdnf + (bN + j) * 256 + chunk * 4;
        const float* xav = &xa[r][chunk * 4];
        double ac0 = 0.0, ac1 = 0.0, ac2 = 0.0, ac3 = 0.0;
#pragma unroll 8
        for (int c4 = 0; c4 < 16; c4++) {
            f32x4 a = *(const f32x4*)(xav + c4 * 16);
            f32x4 bb = *(const f32x4*)(xb + c4 * 16);
            ac0 += (double)a[0] * bb[0];
            ac1 += (double)a[1] * bb[1];
            ac2 += (double)a[2] * bb[2];
            ac3 += (double)a[3] * bb[3];
        }
        double acc = (ac0 + ac1) + (ac2 + ac3);
        acc += __shfl_xor(acc, 1, 64);
        acc += __shfl_xor(acc, 2, 64);
        if (chunk == 0)
            dred[r][q] = 2.0 * acc - xxdn[r] - xxd[bN + j];
    }
    __syncthreads();
    if (t < 8) {
        int used = 0;
        int* dst = idxdn + (bN + n0 + t) * 10;
        for (int rank = 0; rank < 10; rank++) {
            double best = -1.0e300;
            int bi = 0;
#pragma unroll
            for (int i = 0; i < 32; i++) {
                bool ok = !((used >> i) & 1) && dred[t][i] > best;
                if (ok) { best = dred[t][i]; bi = i; }
            }
            used |= (1 << bi);
            dst[rank] = cidx[t][bi];
        }
    }
}

// C_pq[b][n][j] bf16, j<256: P = X.W1^T, j>=256: Q = X.dW^T
// 2 j-tiles per block, arow staged once
__global__ __launch_bounds__(256) void k_pq_gemm(const unsigned short* xdn, const unsigned short* wcat,
                                                 unsigned short* cpq) {
    int j0 = blockIdx.x * 64;
    int n0 = blockIdx.y * 64;
    int b = blockIdx.z;
    int t = threadIdx.x, w = t >> 6, l = t & 63;
    __shared__ __align__(16) unsigned short arow[64 * 264];
    __shared__ __align__(16) unsigned short brow[32 * 264];
    __shared__ float outb[64 * 34];
    {
        int r = t >> 2, seg = t & 3;
        const unsigned short* src = xdn + ((size_t)b * 4096 + n0 + r) * 256 + seg * 64;
        unsigned short* dst = arow + r * 264 + seg * 64;
#pragma unroll
        for (int u = 0; u < 8; u++) *(s16x8*)(dst + 8 * u) = *(const s16x8*)(src + 8 * u);
    }
    {
        int r = t >> 3, seg = t & 7;
        const unsigned short* src = wcat + (size_t)(j0 + r) * 256 + seg * 32;
        unsigned short* dst = brow + r * 264 + seg * 32;
#pragma unroll
        for (int u = 0; u < 4; u++) *(s16x8*)(dst + 8 * u) = *(const s16x8*)(src + 8 * u);
    }
    __syncthreads();
    const unsigned short* ap = arow + (w * 16 + (l & 15)) * 264 + (l >> 4) * 8;
    const unsigned short* bp0 = brow + (l & 15) * 264 + (l >> 4) * 8;
    const unsigned short* bp1 = brow + (16 + (l & 15)) * 264 + (l >> 4) * 8;
#pragma unroll
    for (int jt = 0; jt < 2; jt++) {
        f32x4 acc0 = {0.f, 0.f, 0.f, 0.f}, acc1 = {0.f, 0.f, 0.f, 0.f};
#pragma unroll
        for (int ks = 0; ks < 8; ks++) {
            s16x8 af = *(const s16x8*)(ap + ks * 32);
            acc0 = MFMA(af, *(const s16x8*)(bp0 + ks * 32), acc0);
            acc1 = MFMA(af, *(const s16x8*)(bp1 + ks * 32), acc1);
        }
        __syncthreads();
        if (jt == 0) {
            int r = t >> 3, seg = t & 7;
            const unsigned short* src = wcat + (size_t)(j0 + 32 + r) * 256 + seg * 32;
            unsigned short* dst = brow + r * 264 + seg * 32;
#pragma unroll
            for (int u = 0; u < 4; u++) *(s16x8*)(dst + 8 * u) = *(const s16x8*)(src + 8 * u);
        }
#pragma unroll
        for (int j = 0; j < 4; j++) {
            int row = w * 16 + (l >> 4) * 4 + j;
            outb[row * 34 + (l & 15)] = acc0[j];
            outb[row * 34 + 16 + (l & 15)] = acc1[j];
        }
        __syncthreads();
#pragma unroll
        for (int it = 0; it < 8; it++) {
            int r = it * 8 + (t >> 5);
            int c = t & 31;
            cpq[((size_t)b * 4096 + n0 + r) * 512 + j0 + jt * 32 + c] = f2b(outb[r * 34 + c]);
        }
    }
}

// XCD-affinity swizzle: b = flat & 7; pad rows fused (p==0 / p==127)
__global__ __launch_bounds__(256) void k_combine(const unsigned short* cpq, const int* idxdn,
                                                 const float* bdn, const float* gdn,
                                                 const float* bedn, unsigned short* upad) {
    int flat = blockIdx.x;
    int b = flat & 7;
    int n = flat >> 3;
    int s = n >> 7, p = n & 127;
    int t = threadIdx.x;
    const int* ix = idxdn + ((size_t)b * 4096 + n) * 10;
    float qv = b2f(cpq[((size_t)b * 4096 + n) * 512 + 256 + t]);
    float g = gdn[t], bb = bdn[t], be = bedn[t];
    float a = g * INVBN;
    float d = a * (qv + bb) + be;
    float m = -3.0e38f;
#pragma unroll
    for (int kk = 0; kk < 10; kk++) {
        int j = ix[kk];
        float pv = b2f(cpq[((size_t)b * 4096 + j) * 512 + t]);
        m = fmaxf(m, a * pv + d);
    }
    size_t sb = ((size_t)(b * 32 + s)) * 130;
    upad[(sb + 1 + p) * 256 + t] = f2b(fmaxf(m, 0.f));
    if (p == 0) upad[sb * 256 + t] = 0;
    if (p == 127) upad[(sb + 129) * 256 + t] = 0;
}

__global__ void k_wconv_r(const float* wcv, unsigned short* wr) {
    int o = blockIdx.x, c = threadIdx.x;
#pragma unroll
    for (int i = 0; i < 3; i++) wr[o * 768 + i * 256 + c] = f2b(wcv[o * 768 + c * 3 + i]);
}

__global__ __launch_bounds__(256) void k_conv(const unsigned short* upad, const unsigned short* wr,
                                              const float* bcv, const float* gc,
                                              const float* bec, float* out) {
    int j0 = blockIdx.x * 64;
    int mb = blockIdx.y;
    int b = mb >> 5, s = mb & 31;
    int t = threadIdx.x, w = t >> 6, l = t & 63;
    __shared__ __align__(16) unsigned short at[64 * 72];
    __shared__ __align__(16) unsigned short bt[64 * 72];
    __shared__ float outb[64 * 66];
    f32x4 acc[4];
#pragma unroll
    for (int i = 0; i < 4; i++) acc[i] = (f32x4){0.f, 0.f, 0.f, 0.f};
    const size_t abase = ((size_t)(b * 32 + s)) * 130 * 256;
    for (int kc = 0; kc < 12; kc++) {
        __syncthreads();
        {
            int r = t >> 2, seg = t & 3;
            const unsigned short* src = upad + abase + (size_t)(2 * r) * 256 + kc * 64 + seg * 16;
            unsigned short* dst = at + r * 72 + seg * 16;
            *(s16x8*)dst = *(const s16x8*)src;
            *(s16x8*)(dst + 8) = *(const s16x8*)(src + 8);
            const unsigned short* src2 = wr + (size_t)(j0 + r) * 768 + kc * 64 + seg * 16;
            unsigned short* dst2 = bt + r * 72 + seg * 16;
            *(s16x8*)dst2 = *(const s16x8*)src2;
            *(s16x8*)(dst2 + 8) = *(const s16x8*)(src2 + 8);
        }
        __syncthreads();
#pragma unroll
        for (int ks = 0; ks < 2; ks++) {
            s16x8 af = *(const s16x8*)(at + (w * 16 + (l & 15)) * 72 + ks * 32 + (l >> 4) * 8);
#pragma unroll
            for (int cs = 0; cs < 4; cs++) {
                s16x8 bf = *(const s16x8*)(bt + (cs * 16 + (l & 15)) * 72 + ks * 32 + (l >> 4) * 8);
                acc[cs] = MFMA(af, bf, acc[cs]);
            }
        }
    }
    __syncthreads();
#pragma unroll
    for (int cs = 0; cs < 4; cs++)
#pragma unroll
        for (int j = 0; j < 4; j++)
            outb[(w * 16 + (l >> 4) * 4 + j) * 66 + cs * 16 + (l & 15)] = acc[cs][j];
    __syncthreads();
#pragma unroll
    for (int it = 0; it < 16; it++) {
        int oo = it * 4 + (t >> 6);
        int q = t & 63;
        int o = j0 + oo;
        float v = outb[q * 66 + oo];
        float y = fmaxf(gc[o] * INVBN * (v + bcv[o]) + bec[o], 0.f);
        out[65536 + (((size_t)(b * 256 + o)) * 32 + s) * 64 + q] = y;
    }
}

extern "C" void kernel_launch(void* const* d_in, const int* in_sizes, int n_in,
                              void* d_out, int out_size, void* d_ws, size_t ws_size,
                              hipStream_t stream) {
    const float* sp = (const float*)d_in[0];
    const float* dn = (const float*)d_in[1];
    const float* Wsp = (const float*)d_in[2];
    const float* bsp = (const float*)d_in[3];
    const float* gsp = (const float*)d_in[4];
    const float* besp = (const float*)d_in[5];
    const float* Wdn = (const float*)d_in[6];
    const float* bdn = (const float*)d_in[7];
    const float* gdn = (const float*)d_in[8];
    const float* bedn = (const float*)d_in[9];
    const float* Wcv = (const float*)d_in[10];
    const float* bcv = (const float*)d_in[11];
    const float* gc = (const float*)d_in[12];
    const float* bec = (const float*)d_in[13];
    float* out = (float*)d_out;
    char* ws = (char*)d_ws;

    size_t o_xdn = 0;                          // 16,777,216  (bf16 X)
    size_t o_xdnf = o_xdn + 16777216;          // 33,554,432  (f32 X)
    size_t o_cpq = o_xdnf + 33554432;          // 33,554,432  (bf16 P|Q)
    size_t o_upad = o_cpq + 33554432;          // 17,039,360
    size_t o_wcat = o_upad + 17039360;         // 262,144
    size_t o_wr = o_wcat + 262144;             // 393,216
    size_t o_xx = o_wr + 393216;               // 131,072  (f32)
    size_t o_xxd = o_xx + 131072;              // 262,144  (f64)
    size_t o_cand = o_xxd + 262144;            // 4,194,304 (32 cands)
    size_t o_idx = o_cand + 4194304;           // 1,310,720 (top-10)
    size_t o_usp0 = o_idx + 1310720;           // 262,144
    size_t o_xxsp = o_usp0 + 262144;           // 1,024
    size_t o_idxsp = o_xxsp + 1024;            // 2,048

    unsigned short* xdn = (unsigned short*)(ws + o_xdn);
    float* xdnf = (float*)(ws + o_xdnf);
    unsigned short* cpq = (unsigned short*)(ws + o_cpq);
    unsigned short* upad = (unsigned short*)(ws + o_upad);
    unsigned short* wcat = (unsigned short*)(ws + o_wcat);
    unsigned short* wr = (unsigned short*)(ws + o_wr);
    float* xx = (float*)(ws + o_xx);
    double* xxd = (double*)(ws + o_xxd);
    int* cand = (int*)(ws + o_cand);
    int* idxdn = (int*)(ws + o_idx);
    float* usp0 = (float*)(ws + o_usp0);
    float* xxsp = (float*)(ws + o_xxsp);
    int* idxsp = (int*)(ws + o_idxsp);

    // sparse path
    k_sparse_u0<<<dim3(32, 8), 256, 0, stream>>>(sp, dn, usp0, xxsp);
    k_sparse_knn<<<dim3(32, 8), 64, 0, stream>>>(usp0, xxsp, idxsp);
    k_sparse_edge<<<dim3(32, 8), 256, 0, stream>>>(usp0, idxsp, Wsp, bsp, gsp, besp, out);

    // dense path
    k_build_xdn<<<dim3(128, 8), 256, 0, stream>>>(sp, dn, xdn, xdnf, xx, xxd);
    k_wcat<<<dim3(512), 256, 0, stream>>>(Wdn, wcat);
    k_dense_knn<<<dim3(64, 8), 512, 0, stream>>>(xdn, xx, cand);
    k_rerank<<<dim3(4096), 256, 0, stream>>>(xdnf, xxd, cand, idxdn);
    k_pq_gemm<<<dim3(8, 64, 8), 256, 0, stream>>>(xdn, wcat, cpq);
    k_combine<<<dim3(32768), 256, 0, stream>>>(cpq, idxdn, bdn, gdn, bedn, upad);

    // downsample conv
    k_wconv_r<<<dim3(256), 256, 0, stream>>>(Wcv, wr);
    k_conv<<<dim3(4, 256), 256, 0, stream>>>(upad, wr, bcv, gc, bec, out);
}

// Round 18
// 359.262 us; speedup vs baseline: 1.8678x; 1.0302x over previous
//
#include <hip/hip_runtime.h>

// ---------- helpers ----------
using s16x8 = __attribute__((ext_vector_type(8))) short;
using f32x4 = __attribute__((ext_vector_type(4))) float;

#define MFMA(a, b, c) __builtin_amdgcn_mfma_f32_16x16x32_bf16((a), (b), (c), 0, 0, 0)
#define INVBN 0.9999950000374997f

__device__ __forceinline__ float b2f(unsigned short u) {
    return __uint_as_float(((unsigned int)u) << 16);
}
__device__ __forceinline__ unsigned short f2b(float f) {
    unsigned int x = __float_as_uint(f);
    unsigned int r = x + 0x7FFFu + ((x >> 16) & 1u);
    return (unsigned short)(r >> 16);
}
__device__ __forceinline__ unsigned umin_(unsigned a, unsigned b) { return a < b ? a : b; }
__device__ __forceinline__ unsigned umax_(unsigned a, unsigned b) { return a > b ? a : b; }
#define CE(a, b) { unsigned lo_ = umin_(a, b), hi_ = umax_(a, b); (a) = lo_; (b) = hi_; }

#define BITONIC_RESORT16(v) { \
    _Pragma("unroll") for (int i_ = 0; i_ < 8; i_++) CE(v[i_], v[i_ + 8]) \
    _Pragma("unroll") for (int g_ = 0; g_ < 2; g_++) \
    _Pragma("unroll") for (int i_ = 0; i_ < 4; i_++) CE(v[g_ * 8 + i_], v[g_ * 8 + i_ + 4]) \
    _Pragma("unroll") for (int g_ = 0; g_ < 4; g_++) \
    _Pragma("unroll") for (int i_ = 0; i_ < 2; i_++) CE(v[g_ * 4 + i_], v[g_ * 4 + i_ + 2]) \
    _Pragma("unroll") for (int g_ = 0; g_ < 8; g_++) CE(v[g_ * 2], v[g_ * 2 + 1]) }

// sort8(c8) asc + merge top-16 into v (asc) + resort
#define SORT8_MERGE(c8, v) { \
    CE(c8[0], c8[1]) CE(c8[2], c8[3]) CE(c8[4], c8[5]) CE(c8[6], c8[7]) \
    CE(c8[0], c8[2]) CE(c8[1], c8[3]) CE(c8[4], c8[6]) CE(c8[5], c8[7]) \
    CE(c8[1], c8[2]) CE(c8[5], c8[6]) \
    CE(c8[0], c8[4]) CE(c8[1], c8[5]) CE(c8[2], c8[6]) CE(c8[3], c8[7]) \
    CE(c8[2], c8[4]) CE(c8[3], c8[5]) \
    CE(c8[1], c8[2]) CE(c8[3], c8[4]) CE(c8[5], c8[6]) \
    _Pragma("unroll") for (int i_ = 0; i_ < 8; i_++) v[i_] = umax_(v[i_], c8[7 - i_]); \
    BITONIC_RESORT16(v) }

// cross-lane merge over lanes l^16, l^32 (reversed + max + resort), 2 levels
#define XLANE_MERGE(v) { \
    _Pragma("unroll") for (int lev_ = 0; lev_ < 2; lev_++) { \
        int m_ = lev_ == 0 ? 16 : 32; \
        unsigned o_[16]; \
        _Pragma("unroll") for (int i_ = 0; i_ < 16; i_++) \
            o_[i_] = (unsigned)__shfl_xor((int)v[15 - i_], m_, 64); \
        _Pragma("unroll") for (int i_ = 0; i_ < 16; i_++) v[i_] = umax_(v[i_], o_[i_]); \
        BITONIC_RESORT16(v) } }

// ---------- sparse path (all f32 scalar; tiny) ----------
__global__ __launch_bounds__(256) void k_sparse_u0(const float* sp, const float* dn,
                                                   float* usp0, float* xxsp) {
    int s = blockIdx.x, b = blockIdx.y, c = threadIdx.x;
    float v;
    if (c < 128) {
        v = sp[(b * 128 + c) * 32 + s];
    } else {
        const float* row = dn + ((size_t)((b * 128 + (c - 128)) * 32 + s)) * 128;
        float m = -3.0e38f;
        for (int p = 0; p < 128; p++) m = fmaxf(m, row[p]);
        v = m;
    }
    usp0[(size_t)(b * 32 + s) * 256 + c] = v;
    __shared__ float red[256];
    red[c] = v * v;
    __syncthreads();
    for (int st = 128; st > 0; st >>= 1) {
        if (c < st) red[c] += red[c + st];
        __syncthreads();
    }
    if (c == 0) xxsp[b * 32 + s] = red[0];
}

__global__ __launch_bounds__(64) void k_sparse_knn(const float* usp0, const float* xxsp, int* idxsp) {
    int n = blockIdx.x, b = blockIdx.y, t = threadIdx.x;
    float nd = -3.0e38f;
    if (t < 32) {
        const float* xn = usp0 + (size_t)(b * 32 + n) * 256;
        const float* xj = usp0 + (size_t)(b * 32 + t) * 256;
        float inner = 0.f;
        for (int c = 0; c < 256; c++) inner += xn[c] * xj[c];
        nd = 2.f * inner - xxsp[b * 32 + n] - xxsp[b * 32 + t];
    }
    float best1 = -3.0e38f, best2 = -3.0e38f;
    int i1 = 0, i2 = 0;
    for (int jj = 0; jj < 32; jj++) {
        float vv = __shfl(nd, jj, 64);
        if (vv > best1) { best2 = best1; i2 = i1; best1 = vv; i1 = jj; }
        else if (vv > best2) { best2 = vv; i2 = jj; }
    }
    if (t == 0) {
        idxsp[(b * 32 + n) * 2] = i1;
        idxsp[(b * 32 + n) * 2 + 1] = i2;
    }
}

__global__ __launch_bounds__(256) void k_sparse_edge(const float* usp0, const int* idxsp,
                                                     const float* wsp, const float* bsp,
                                                     const float* gsp, const float* besp,
                                                     float* out) {
    int n = blockIdx.x, b = blockIdx.y, t = threadIdx.x;
    __shared__ float ctr[256], nb0[256], nb1[256];
    int i0 = idxsp[(b * 32 + n) * 2], i1 = idxsp[(b * 32 + n) * 2 + 1];
    ctr[t] = usp0[(size_t)(b * 32 + n) * 256 + t];
    nb0[t] = usp0[(size_t)(b * 32 + i0) * 256 + t];
    nb1[t] = usp0[(size_t)(b * 32 + i1) * 256 + t];
    __syncthreads();
    const float* wrow = wsp + (size_t)t * 512;
    float a0 = 0.f, a1 = 0.f, ac = 0.f;
    for (int c = 0; c < 256; c++) {
        float w1 = wrow[c], w2 = wrow[256 + c];
        float cc = ctr[c];
        a0 += (nb0[c] - cc) * w1;
        a1 += (nb1[c] - cc) * w1;
        ac += cc * w2;
    }
    float g = gsp[t], bb = bsp[t], be = besp[t];
    float h0 = g * INVBN * (a0 + ac + bb) + be;
    float h1 = g * INVBN * (a1 + ac + bb) + be;
    out[((size_t)(b * 256 + t)) * 32 + n] = fmaxf(fmaxf(h0, h1), 0.f);
}

// ---------- dense path ----------
// build + fused row-norm (f64 exact): xx = sum(tile^2) + sum(sp^2) per stroke
__global__ __launch_bounds__(256) void k_build_xdn(const float* sp, const float* dn,
                                                   unsigned short* xdn, float* xdnf,
                                                   float* xx, double* xxd) {
    int bx = blockIdx.x;
    int s = bx >> 2, q = bx & 3;
    int b = blockIdx.y, t = threadIdx.x;
    __shared__ float tile[32 * 131];
    __shared__ double spred[128];
    __shared__ double spsum_sh;
    float spv = 0.f;
    if (t >= 128) spv = sp[(b * 128 + (t - 128)) * 32 + s];
    int pl = t & 31, ch = t >> 5;
#pragma unroll
    for (int it = 0; it < 16; it++) {
        int c = it * 8 + ch;
        tile[pl * 131 + c] = dn[((size_t)((b * 128 + c) * 32 + s)) * 128 + q * 32 + pl];
    }
    if (t >= 128) spred[t - 128] = (double)spv * spv;
    __syncthreads();
    if (t == 0) {
        double ssum = 0.0;
        for (int i = 0; i < 128; i++) ssum += spred[i];
        spsum_sh = ssum;
    }
    for (int pp = 0; pp < 32; pp++) {
        float v = (t < 128) ? tile[pp * 131 + t] : spv;
        size_t row = (size_t)(b * 4096) + s * 128 + q * 32 + pp;
        xdnf[row * 256 + t] = v;
        xdn[row * 256 + t] = f2b(v);
    }
    __syncthreads();
    {
        int pp = t >> 3, seg = t & 7;
        double ps = 0.0;
#pragma unroll
        for (int i = 0; i < 16; i++) {
            float v = tile[pp * 131 + seg * 16 + i];
            ps += (double)v * v;
        }
        ps += __shfl_xor(ps, 1, 64);
        ps += __shfl_xor(ps, 2, 64);
        ps += __shfl_xor(ps, 4, 64);
        if (seg == 0) {
            double tot = ps + spsum_sh;
            size_t row = (size_t)(b * 4096) + s * 128 + q * 32 + pp;
            xx[row] = (float)tot;
            xxd[row] = tot;
        }
    }
}

__global__ __launch_bounds__(256) void k_wcat(const float* wdn, unsigned short* wcat) {
    int j = blockIdx.x, c = threadIdx.x;
    if (j < 256) {
        wcat[j * 256 + c] = f2b(wdn[j * 512 + c]);
    } else {
        int o = j - 256;
        wcat[j * 256 + c] = f2b(wdn[o * 512 + 256 + c] - wdn[o * 512 + c]);
    }
}

// phase-1 kNN: 8 waves, tile-parity groups, 2 ROW-GROUPS per wave (32 rows).
// R15/R17 form (proven 159us): direct global->LDS staging, 34KB LDS alias.
__global__ __launch_bounds__(512, 4) void k_dense_knn(const unsigned short* xdn, const float* xx, int* cand) {
    int b = blockIdx.y;
    int rb = blockIdx.x >> 1;
    int h = blockIdx.x & 1;
    int r0 = rb * 128;
    int c0base = h * 2048;
    int t = threadIdx.x;
    int g = t >> 8;          // tile-parity group (waves 0-3 / 4-7)
    int tg = t & 255;        // thread-in-group
    int wr = (t >> 6) & 3;   // row-wave within group
    int l = t & 63;
    __shared__ __align__(16) char smem_raw[2 * 32 * 264 * 2 + 256];   // 34048 B
    unsigned short* acol = (unsigned short*)smem_raw;
    float* xxc = (float*)(smem_raw + 2 * 32 * 264 * 2);
    unsigned* g1k = (unsigned*)smem_raw;   // ALIAS: valid only after post-loop barrier
    size_t bN = (size_t)b * 4096;
    int row0 = wr * 32 + (l & 15);   // relative row of rg0
    int row1 = row0 + 16;            // rg1

    unsigned short* acolg = acol + g * (32 * 264);

    // tile-invariant B fragments (my 2 rows) in registers
    s16x8 bfrag0[8], bfrag1[8];
    {
        const s16x8* gb0 = (const s16x8*)(xdn + (bN + r0 + row0) * 256 + (l >> 4) * 8);
        const s16x8* gb1 = (const s16x8*)(xdn + (bN + r0 + row1) * 256 + (l >> 4) * 8);
#pragma unroll
        for (int ks = 0; ks < 8; ks++) { bfrag0[ks] = gb0[ks * 4]; bfrag1[ks] = gb1[ks * 4]; }
    }

    unsigned v16a[16], v16b[16];
#pragma unroll
    for (int i = 0; i < 16; i++) { v16a[i] = 0u; v16b[i] = 0u; }

    for (int ct = 0; ct < 32; ct++) {
        int c0 = c0base + (ct * 2 + g) * 32;
        __syncthreads();
        {
            int r = tg & 31, seg = tg >> 5;
            const s16x8* src = (const s16x8*)(xdn + (bN + c0 + r) * 256 + seg * 32);
            s16x8* dst = (s16x8*)(acolg + r * 264 + seg * 32);
#pragma unroll
            for (int u = 0; u < 4; u++) dst[u] = src[u];
        }
        if (tg < 32) xxc[g * 32 + tg] = xx[bN + c0 + tg];
        __syncthreads();
        f32x4 a00 = {0.f, 0.f, 0.f, 0.f}, a01 = {0.f, 0.f, 0.f, 0.f};
        f32x4 a10 = {0.f, 0.f, 0.f, 0.f}, a11 = {0.f, 0.f, 0.f, 0.f};
        const unsigned short* ap0 = acolg + (l & 15) * 264 + (l >> 4) * 8;
        const unsigned short* ap1 = ap0 + 16 * 264;
#pragma unroll
        for (int ks = 0; ks < 8; ks++) {
            s16x8 ca = *(const s16x8*)(ap0 + ks * 32);
            s16x8 cb = *(const s16x8*)(ap1 + ks * 32);
            a00 = MFMA(ca, bfrag0[ks], a00);
            a01 = MFMA(cb, bfrag0[ks], a01);
            a10 = MFMA(ca, bfrag1[ks], a10);
            a11 = MFMA(cb, bfrag1[ks], a11);
        }
        {
            unsigned c8[8];
#pragma unroll
            for (int j = 0; j < 4; j++) {
                int cl0 = (l >> 4) * 4 + j;
                float d0 = 2.f * a00[j] - xxc[g * 32 + cl0];
                unsigned u0 = __float_as_uint(d0);
                u0 ^= ((unsigned)((int)u0 >> 31)) | 0x80000000u;
                c8[j] = (u0 & 0xFFFFF000u) | (unsigned)(c0 + cl0);
                int cl1 = cl0 + 16;
                float d1 = 2.f * a01[j] - xxc[g * 32 + cl1];
                unsigned u1 = __float_as_uint(d1);
                u1 ^= ((unsigned)((int)u1 >> 31)) | 0x80000000u;
                c8[4 + j] = (u1 & 0xFFFFF000u) | (unsigned)(c0 + cl1);
            }
            SORT8_MERGE(c8, v16a)
        }
        {
            unsigned c8[8];
#pragma unroll
            for (int j = 0; j < 4; j++) {
                int cl0 = (l >> 4) * 4 + j;
                float d0 = 2.f * a10[j] - xxc[g * 32 + cl0];
                unsigned u0 = __float_as_uint(d0);
                u0 ^= ((unsigned)((int)u0 >> 31)) | 0x80000000u;
                c8[j] = (u0 & 0xFFFFF000u) | (unsigned)(c0 + cl0);
                int cl1 = cl0 + 16;
                float d1 = 2.f * a11[j] - xxc[g * 32 + cl1];
                unsigned u1 = __float_as_uint(d1);
                u1 ^= ((unsigned)((int)u1 >> 31)) | 0x80000000u;
                c8[4 + j] = (u1 & 0xFFFFF000u) | (unsigned)(c0 + cl1);
            }
            SORT8_MERGE(c8, v16b)
        }
    }

    XLANE_MERGE(v16a)
    XLANE_MERGE(v16b)

    // fence: all waves done with acol before g1k (aliased) is written
    __syncthreads();
    if (g == 1 && (l >> 4) == 0) {
#pragma unroll
        for (int i = 0; i < 16; i++) {
            g1k[row0 * 16 + i] = v16a[i];
            g1k[row1 * 16 + i] = v16b[i];
        }
    }
    __syncthreads();
    if (g == 0 && (l >> 4) == 0) {
        {
            unsigned o[16];
#pragma unroll
            for (int i = 0; i < 16; i++) o[i] = g1k[row0 * 16 + 15 - i];
#pragma unroll
            for (int i = 0; i < 16; i++) v16a[i] = umax_(v16a[i], o[i]);
            BITONIC_RESORT16(v16a)
            int* dst = cand + (bN + r0 + row0) * 32 + h * 16;
#pragma unroll
            for (int i = 0; i < 16; i++) dst[i] = (int)(v16a[i] & 0xFFFu);
        }
        {
            unsigned o[16];
#pragma unroll
            for (int i = 0; i < 16; i++) o[i] = g1k[row1 * 16 + 15 - i];
#pragma unroll
            for (int i = 0; i < 16; i++) v16b[i] = umax_(v16b[i], o[i]);
            BITONIC_RESORT16(v16b)
            int* dst = cand + (bN + r0 + row1) * 32 + h * 16;
#pragma unroll
            for (int i = 0; i < 16; i++) dst[i] = (int)(v16b[i] & 0xFFFu);
        }
    }
}

// phase-2: exact f64 re-rank of 32 candidates -> top-10 indices.
// Coalesced gather (4 lanes/candidate) + XCD-affinity swizzle (b = flat & 7).
__global__ __launch_bounds__(256) void k_rerank(const float* xdnf, const double* xxd,
                                                const int* cand, int* idxdn) {
    int flat = blockIdx.x;
    int b = flat & 7;
    int n0 = (flat >> 3) * 8;
    int t = threadIdx.x;
    int r = t >> 5;          // row 0..7
    int qg = (t >> 2) & 7;   // candidate-in-pass 0..7
    int chunk = t & 3;       // 16B chunk within a 64B line
    __shared__ float xa[8][260];
    __shared__ double dred[8][32];
    __shared__ double xxdn[8];
    __shared__ int cidx[8][32];
    size_t bN = (size_t)b * 4096;
    {
        int rr = t >> 5, qq = t & 31;
        const float* src = xdnf + (bN + n0 + rr) * 256 + qq * 8;
        *(f32x4*)&xa[rr][qq * 8] = *(const f32x4*)src;
        *(f32x4*)&xa[rr][qq * 8 + 4] = *(const f32x4*)(src + 4);
        if (t < 8) xxdn[t] = xxd[bN + n0 + t];
        cidx[rr][qq] = cand[(bN + n0 + rr) * 32 + qq];
    }
    __syncthreads();
#pragma unroll
    for (int p = 0; p < 4; p++) {
        int q = p * 8 + qg;
        int j = cidx[r][q];
        const float* xb = xdnf + (bN + j) * 256 + chunk * 4;
        const float* xav = &xa[r][chunk * 4];
        double ac0 = 0.0, ac1 = 0.0, ac2 = 0.0, ac3 = 0.0;
#pragma unroll 8
        for (int c4 = 0; c4 < 16; c4++) {
            f32x4 a = *(const f32x4*)(xav + c4 * 16);
            f32x4 bb = *(const f32x4*)(xb + c4 * 16);
            ac0 += (double)a[0] * bb[0];
            ac1 += (double)a[1] * bb[1];
            ac2 += (double)a[2] * bb[2];
            ac3 += (double)a[3] * bb[3];
        }
        double acc = (ac0 + ac1) + (ac2 + ac3);
        acc += __shfl_xor(acc, 1, 64);
        acc += __shfl_xor(acc, 2, 64);
        if (chunk == 0)
            dred[r][q] = 2.0 * acc - xxdn[r] - xxd[bN + j];
    }
    __syncthreads();
    if (t < 8) {
        int used = 0;
        int* dst = idxdn + (bN + n0 + t) * 10;
        for (int rank = 0; rank < 10; rank++) {
            double best = -1.0e300;
            int bi = 0;
#pragma unroll
            for (int i = 0; i < 32; i++) {
                bool ok = !((used >> i) & 1) && dred[t][i] > best;
                if (ok) { best = dred[t][i]; bi = i; }
            }
            used |= (1 << bi);
            dst[rank] = cidx[t][bi];
        }
    }
}

// C_pq[b][n][j] bf16, j<256: P = X.W1^T, j>=256: Q = X.dW^T
// ALL 512 j-columns per block: arow staged ONCE (was 8x re-staged across
// j-blocks -> 134MB of xdn re-reads; now 16.7MB). 16 j-tiles of 32, same
// proven barrier pipeline as the 2-tile version. Grid 512 blocks = 2/CU exact.
__global__ __launch_bounds__(256) void k_pq_gemm(const unsigned short* xdn, const unsigned short* wcat,
                                                 unsigned short* cpq) {
    int n0 = blockIdx.x * 64;
    int b = blockIdx.y;
    int t = threadIdx.x, w = t >> 6, l = t & 63;
    __shared__ __align__(16) unsigned short arow[64 * 264];
    __shared__ __align__(16) unsigned short brow[32 * 264];
    __shared__ float outb[64 * 34];
    {
        int r = t >> 2, seg = t & 3;
        const unsigned short* src = xdn + ((size_t)b * 4096 + n0 + r) * 256 + seg * 64;
        unsigned short* dst = arow + r * 264 + seg * 64;
#pragma unroll
        for (int u = 0; u < 8; u++) *(s16x8*)(dst + 8 * u) = *(const s16x8*)(src + 8 * u);
    }
    {
        int r = t >> 3, seg = t & 7;
        const unsigned short* src = wcat + (size_t)r * 256 + seg * 32;
        unsigned short* dst = brow + r * 264 + seg * 32;
#pragma unroll
        for (int u = 0; u < 4; u++) *(s16x8*)(dst + 8 * u) = *(const s16x8*)(src + 8 * u);
    }
    __syncthreads();
    const unsigned short* ap = arow + (w * 16 + (l & 15)) * 264 + (l >> 4) * 8;
    const unsigned short* bp0 = brow + (l & 15) * 264 + (l >> 4) * 8;
    const unsigned short* bp1 = brow + (16 + (l & 15)) * 264 + (l >> 4) * 8;
    for (int jt = 0; jt < 16; jt++) {
        f32x4 acc0 = {0.f, 0.f, 0.f, 0.f}, acc1 = {0.f, 0.f, 0.f, 0.f};
#pragma unroll
        for (int ks = 0; ks < 8; ks++) {
            s16x8 af = *(const s16x8*)(ap + ks * 32);
            acc0 = MFMA(af, *(const s16x8*)(bp0 + ks * 32), acc0);
            acc1 = MFMA(af, *(const s16x8*)(bp1 + ks * 32), acc1);
        }
        __syncthreads();   // brow reads done; prev outb stores done (stores precede this barrier)
        if (jt < 15) {
            int r = t >> 3, seg = t & 7;
            const unsigned short* src = wcat + (size_t)((jt + 1) * 32 + r) * 256 + seg * 32;
            unsigned short* dst = brow + r * 264 + seg * 32;
#pragma unroll
            for (int u = 0; u < 4; u++) *(s16x8*)(dst + 8 * u) = *(const s16x8*)(src + 8 * u);
        }
#pragma unroll
        for (int j = 0; j < 4; j++) {
            int row = w * 16 + (l >> 4) * 4 + j;
            outb[row * 34 + (l & 15)] = acc0[j];
            outb[row * 34 + 16 + (l & 15)] = acc1[j];
        }
        __syncthreads();   // outb visible + new brow staged
#pragma unroll
        for (int it = 0; it < 8; it++) {
            int r = it * 8 + (t >> 5);
            int c = t & 31;
            cpq[((size_t)b * 4096 + n0 + r) * 512 + jt * 32 + c] = f2b(outb[r * 34 + c]);
        }
    }
}

// XCD-affinity swizzle: b = flat & 7; pad rows fused (p==0 / p==127)
__global__ __launch_bounds__(256) void k_combine(const unsigned short* cpq, const int* idxdn,
                                                 const float* bdn, const float* gdn,
                                                 const float* bedn, unsigned short* upad) {
    int flat = blockIdx.x;
    int b = flat & 7;
    int n = flat >> 3;
    int s = n >> 7, p = n & 127;
    int t = threadIdx.x;
    const int* ix = idxdn + ((size_t)b * 4096 + n) * 10;
    float qv = b2f(cpq[((size_t)b * 4096 + n) * 512 + 256 + t]);
    float g = gdn[t], bb = bdn[t], be = bedn[t];
    float a = g * INVBN;
    float d = a * (qv + bb) + be;
    float m = -3.0e38f;
#pragma unroll
    for (int kk = 0; kk < 10; kk++) {
        int j = ix[kk];
        float pv = b2f(cpq[((size_t)b * 4096 + j) * 512 + t]);
        m = fmaxf(m, a * pv + d);
    }
    size_t sb = ((size_t)(b * 32 + s)) * 130;
    upad[(sb + 1 + p) * 256 + t] = f2b(fmaxf(m, 0.f));
    if (p == 0) upad[sb * 256 + t] = 0;
    if (p == 127) upad[(sb + 129) * 256 + t] = 0;
}

__global__ void k_wconv_r(const float* wcv, unsigned short* wr) {
    int o = blockIdx.x, c = threadIdx.x;
#pragma unroll
    for (int i = 0; i < 3; i++) wr[o * 768 + i * 256 + c] = f2b(wcv[o * 768 + c * 3 + i]);
}

__global__ __launch_bounds__(256) void k_conv(const unsigned short* upad, const unsigned short* wr,
                                              const float* bcv, const float* gc,
                                              const float* bec, float* out) {
    int j0 = blockIdx.x * 64;
    int mb = blockIdx.y;
    int b = mb >> 5, s = mb & 31;
    int t = threadIdx.x, w = t >> 6, l = t & 63;
    __shared__ __align__(16) unsigned short at[64 * 72];
    __shared__ __align__(16) unsigned short bt[64 * 72];
    __shared__ float outb[64 * 66];
    f32x4 acc[4];
#pragma unroll
    for (int i = 0; i < 4; i++) acc[i] = (f32x4){0.f, 0.f, 0.f, 0.f};
    const size_t abase = ((size_t)(b * 32 + s)) * 130 * 256;
    for (int kc = 0; kc < 12; kc++) {
        __syncthreads();
        {
            int r = t >> 2, seg = t & 3;
            const unsigned short* src = upad + abase + (size_t)(2 * r) * 256 + kc * 64 + seg * 16;
            unsigned short* dst = at + r * 72 + seg * 16;
            *(s16x8*)dst = *(const s16x8*)src;
            *(s16x8*)(dst + 8) = *(const s16x8*)(src + 8);
            const unsigned short* src2 = wr + (size_t)(j0 + r) * 768 + kc * 64 + seg * 16;
            unsigned short* dst2 = bt + r * 72 + seg * 16;
            *(s16x8*)dst2 = *(const s16x8*)src2;
            *(s16x8*)(dst2 + 8) = *(const s16x8*)(src2 + 8);
        }
        __syncthreads();
#pragma unroll
        for (int ks = 0; ks < 2; ks++) {
            s16x8 af = *(const s16x8*)(at + (w * 16 + (l & 15)) * 72 + ks * 32 + (l >> 4) * 8);
#pragma unroll
            for (int cs = 0; cs < 4; cs++) {
                s16x8 bf = *(const s16x8*)(bt + (cs * 16 + (l & 15)) * 72 + ks * 32 + (l >> 4) * 8);
                acc[cs] = MFMA(af, bf, acc[cs]);
            }
        }
    }
    __syncthreads();
#pragma unroll
    for (int cs = 0; cs < 4; cs++)
#pragma unroll
        for (int j = 0; j < 4; j++)
            outb[(w * 16 + (l >> 4) * 4 + j) * 66 + cs * 16 + (l & 15)] = acc[cs][j];
    __syncthreads();
#pragma unroll
    for (int it = 0; it < 16; it++) {
        int oo = it * 4 + (t >> 6);
        int q = t & 63;
        int o = j0 + oo;
        float v = outb[q * 66 + oo];
        float y = fmaxf(gc[o] * INVBN * (v + bcv[o]) + bec[o], 0.f);
        out[65536 + (((size_t)(b * 256 + o)) * 32 + s) * 64 + q] = y;
    }
}

extern "C" void kernel_launch(void* const* d_in, const int* in_sizes, int n_in,
                              void* d_out, int out_size, void* d_ws, size_t ws_size,
                              hipStream_t stream) {
    const float* sp = (const float*)d_in[0];
    const float* dn = (const float*)d_in[1];
    const float* Wsp = (const float*)d_in[2];
    const float* bsp = (const float*)d_in[3];
    const float* gsp = (const float*)d_in[4];
    const float* besp = (const float*)d_in[5];
    const float* Wdn = (const float*)d_in[6];
    const float* bdn = (const float*)d_in[7];
    const float* gdn = (const float*)d_in[8];
    const float* bedn = (const float*)d_in[9];
    const float* Wcv = (const float*)d_in[10];
    const float* bcv = (const float*)d_in[11];
    const float* gc = (const float*)d_in[12];
    const float* bec = (const float*)d_in[13];
    float* out = (float*)d_out;
    char* ws = (char*)d_ws;

    size_t o_xdn = 0;                          // 16,777,216  (bf16 X)
    size_t o_xdnf = o_xdn + 16777216;          // 33,554,432  (f32 X)
    size_t o_cpq = o_xdnf + 33554432;          // 33,554,432  (bf16 P|Q)
    size_t o_upad = o_cpq + 33554432;          // 17,039,360
    size_t o_wcat = o_upad + 17039360;         // 262,144
    size_t o_wr = o_wcat + 262144;             // 393,216
    size_t o_xx = o_wr + 393216;               // 131,072  (f32)
    size_t o_xxd = o_xx + 131072;              // 262,144  (f64)
    size_t o_cand = o_xxd + 262144;            // 4,194,304 (32 cands)
    size_t o_idx = o_cand + 4194304;           // 1,310,720 (top-10)
    size_t o_usp0 = o_idx + 1310720;           // 262,144
    size_t o_xxsp = o_usp0 + 262144;           // 1,024
    size_t o_idxsp = o_xxsp + 1024;            // 2,048

    unsigned short* xdn = (unsigned short*)(ws + o_xdn);
    float* xdnf = (float*)(ws + o_xdnf);
    unsigned short* cpq = (unsigned short*)(ws + o_cpq);
    unsigned short* upad = (unsigned short*)(ws + o_upad);
    unsigned short* wcat = (unsigned short*)(ws + o_wcat);
    unsigned short* wr = (unsigned short*)(ws + o_wr);
    float* xx = (float*)(ws + o_xx);
    double* xxd = (double*)(ws + o_xxd);
    int* cand = (int*)(ws + o_cand);
    int* idxdn = (int*)(ws + o_idx);
    float* usp0 = (float*)(ws + o_usp0);
    float* xxsp = (float*)(ws + o_xxsp);
    int* idxsp = (int*)(ws + o_idxsp);

    // sparse path
    k_sparse_u0<<<dim3(32, 8), 256, 0, stream>>>(sp, dn, usp0, xxsp);
    k_sparse_knn<<<dim3(32, 8), 64, 0, stream>>>(usp0, xxsp, idxsp);
    k_sparse_edge<<<dim3(32, 8), 256, 0, stream>>>(usp0, idxsp, Wsp, bsp, gsp, besp, out);

    // dense path
    k_build_xdn<<<dim3(128, 8), 256, 0, stream>>>(sp, dn, xdn, xdnf, xx, xxd);
    k_wcat<<<dim3(512), 256, 0, stream>>>(Wdn, wcat);
    k_dense_knn<<<dim3(64, 8), 512, 0, stream>>>(xdn, xx, cand);
    k_rerank<<<dim3(4096), 256, 0, stream>>>(xdnf, xxd, cand, idxdn);
    k_pq_gemm<<<dim3(64, 8), 256, 0, stream>>>(xdn, wcat, cpq);
    k_combine<<<dim3(32768), 256, 0, stream>>>(cpq, idxdn, bdn, gdn, bedn, upad);

    // downsample conv
    k_wconv_r<<<dim3(256), 256, 0, stream>>>(Wcv, wr);
    k_conv<<<dim3(4, 256), 256, 0, stream>>>(upad, wr, bcv, gc, bec, out);
}